// Round 1
// baseline (385.568 us; speedup 1.0000x reference)
//
#include <hip/hip_runtime.h>
#include <stdint.h>

#define NB 4
#define LD 4096
#define SD 4096
#define CD 256

static constexpr long CHUNK = (long)NB * LD * SD;     // 67108864 elements per [N,L,S] output
static constexpr float SCALE = 0.0625f;               // 1/sqrt(256)
static constexpr float INV_TC = 1.0f / 25.6f;         // 1/(0.1*256)
static constexpr float THRV = 0.2f;

typedef __attribute__((ext_vector_type(8))) short bf16x8;
typedef __attribute__((ext_vector_type(4))) float f32x4;

__device__ __forceinline__ unsigned short f2bf(float x) {
  unsigned int u = __float_as_uint(x);
  return (unsigned short)((u + 0x7FFFu + ((u >> 16) & 1u)) >> 16);
}

__device__ __forceinline__ void gload_lds16(const void* g, void* l) {
  __builtin_amdgcn_global_load_lds((const __attribute__((address_space(1))) void*)g,
                                   (__attribute__((address_space(3))) void*)l, 16, 0, 0);
}

// ---------------- Kernel 1: scale -> bf16 copies + fp32 squared norms ----------------
__global__ __launch_bounds__(256) void k_prep(const float* __restrict__ f0,
                                              const float* __restrict__ f1,
                                              unsigned short* __restrict__ abf,
                                              unsigned short* __restrict__ bbf,
                                              float* __restrict__ sq0,
                                              float* __restrict__ sq1) {
  int wid = threadIdx.x >> 6, lane = threadIdx.x & 63;
  long row = (long)blockIdx.x * 4 + wid;               // over N*(L+S) rows
  const long nl = (long)NB * LD;
  const float* src;
  unsigned short* dst;
  float* sqd;
  if (row < nl) {
    src = f0 + row * CD; dst = abf + row * CD; sqd = sq0 + row;
  } else {
    long r = row - nl;
    src = f1 + r * CD; dst = bbf + r * CD; sqd = sq1 + r;
  }
  float4 v = reinterpret_cast<const float4*>(src)[lane];
  v.x *= SCALE; v.y *= SCALE; v.z *= SCALE; v.w *= SCALE;
  ushort4 o;
  o.x = f2bf(v.x); o.y = f2bf(v.y); o.z = f2bf(v.z); o.w = f2bf(v.w);
  reinterpret_cast<ushort4*>(dst)[lane] = o;
  float s = v.x * v.x + v.y * v.y + v.z * v.z + v.w * v.w;
  #pragma unroll
  for (int m = 1; m < 64; m <<= 1) s += __shfl_xor(s, m);
  if (lane == 0) *sqd = s;
}

// ---------------- Kernel 2: bf16 MFMA GEMM -> sim write + exp row/col sums ----------------
// 128x128 tile, BK=64, 4 waves each owning 64x64. LDS XOR-swizzled via pre-swizzled
// global source (global_load_lds writes linearly; read applies the same XOR).
__global__ __launch_bounds__(256) void k_gemm(const unsigned short* __restrict__ abf,
                                              const unsigned short* __restrict__ bbf,
                                              const float* __restrict__ sq0,
                                              const float* __restrict__ sq1,
                                              float* __restrict__ simout,
                                              float* __restrict__ rowsum,
                                              float* __restrict__ colsum) {
  __shared__ char lds[32768];                          // A: [0,16K), B: [16K,32K)
  int t = threadIdx.x;
  int wid = t >> 6, lane = t & 63;
  int bz = blockIdx.z;
  long tileM = (long)blockIdx.y * 128;
  long tileS = (long)blockIdx.x * 128;
  const char* aB = (const char*)(abf + ((long)bz * LD + tileM) * CD);
  const char* bB = (const char*)(bbf + ((long)bz * SD + tileS) * CD);

  int srow = t >> 3;                                   // 0..31 staging row
  int scolb = (t & 7) << 4;                            // 0..112 staging byte col
  int wrb = (wid >> 1) << 6;                           // wave row base (0/64)
  int wcb = (wid & 1) << 6;                            // wave col base (0/64)
  int lrow = lane & 15;
  int kgrp = lane >> 4;

  f32x4 acc[4][4];
  #pragma unroll
  for (int m = 0; m < 4; ++m)
    #pragma unroll
    for (int n = 0; n < 4; ++n)
      acc[m][n] = (f32x4){0.f, 0.f, 0.f, 0.f};

  for (int kt = 0; kt < 4; ++kt) {
    #pragma unroll
    for (int i = 0; i < 4; ++i) {
      int row = i * 32 + srow;
      int sc = scolb ^ ((row & 7) << 4);               // pre-swizzle source col
      gload_lds16(aB + (long)row * (CD * 2) + kt * 128 + sc,
                  lds + i * 4096 + (wid << 10));
      gload_lds16(bB + (long)row * (CD * 2) + kt * 128 + sc,
                  lds + 16384 + i * 4096 + (wid << 10));
    }
    __syncthreads();
    #pragma unroll
    for (int ks = 0; ks < 2; ++ks) {
      int kb = ks * 64 + kgrp * 16;                    // byte offset of this lane's 8 bf16
      bf16x8 af[4], bfr[4];
      #pragma unroll
      for (int m = 0; m < 4; ++m) {
        int r = wrb + m * 16 + lrow;
        af[m] = *(const bf16x8*)(lds + r * 128 + (kb ^ ((r & 7) << 4)));
      }
      #pragma unroll
      for (int n = 0; n < 4; ++n) {
        int r = wcb + n * 16 + lrow;
        bfr[n] = *(const bf16x8*)(lds + 16384 + r * 128 + (kb ^ ((r & 7) << 4)));
      }
      #pragma unroll
      for (int m = 0; m < 4; ++m)
        #pragma unroll
        for (int n = 0; n < 4; ++n)
          acc[m][n] = __builtin_amdgcn_mfma_f32_16x16x32_bf16(af[m], bfr[n], acc[m][n], 0, 0, 0);
    }
    __syncthreads();
  }

  // Epilogue: sim = -sqrt(max(sq0+sq1-2*inner,0))/25.6 ; accumulate exp sums
  long gcol0 = (long)bz * SD + tileS + wcb;
  float sq1v[4];
  #pragma unroll
  for (int n = 0; n < 4; ++n) sq1v[n] = sq1[gcol0 + n * 16 + lrow];

  float ce[4] = {0.f, 0.f, 0.f, 0.f};
  #pragma unroll
  for (int m = 0; m < 4; ++m) {
    #pragma unroll
    for (int i = 0; i < 4; ++i) {
      int lr = m * 16 + kgrp * 4 + i;                  // C/D layout: row=(lane>>4)*4+reg
      long gl = tileM + wrb + lr;
      float s0 = sq0[(long)bz * LD + gl];
      float* srow_p = simout + ((long)bz * LD + gl) * SD + tileS + wcb;
      float rs = 0.f;
      #pragma unroll
      for (int n = 0; n < 4; ++n) {
        float inner = acc[m][n][i];
        float d2 = fmaxf(s0 + sq1v[n] - 2.0f * inner, 0.f);
        float sv = -__builtin_sqrtf(d2) * INV_TC;
        srow_p[n * 16 + lrow] = sv;
        float e = __expf(sv);
        rs += e;
        ce[n] += e;
      }
      #pragma unroll
      for (int d = 1; d < 16; d <<= 1) rs += __shfl_xor(rs, d);
      if (lrow == 0) atomicAdd(&rowsum[(long)bz * LD + gl], rs);
    }
  }
  #pragma unroll
  for (int n = 0; n < 4; ++n) {
    float cs = ce[n];
    cs += __shfl_xor(cs, 16);
    cs += __shfl_xor(cs, 32);
    if (kgrp == 0) atomicAdd(&colsum[gcol0 + n * 16 + lrow], cs);
  }
}

// ---------------- Kernel 3: dual softmax + packed row/col argmax ----------------
// block = 64 rows x 512 cols tile, grid (S/512, L/64, N)
__global__ __launch_bounds__(256) void k_softmax(const float* __restrict__ sim,
                                                 const float* __restrict__ rowsum,
                                                 const float* __restrict__ colsum,
                                                 float* __restrict__ conf,
                                                 float* __restrict__ conf0,
                                                 float* __restrict__ conf1,
                                                 unsigned long long* __restrict__ rowpack,
                                                 unsigned long long* __restrict__ colpack) {
  __shared__ unsigned long long rmx[64];
  __shared__ unsigned long long cmx[512];
  int t = threadIdx.x;
  if (t < 64) rmx[t] = 0ull;
  cmx[t] = 0ull;
  cmx[t + 256] = 0ull;
  __syncthreads();

  int n = blockIdx.z;
  long rbase = (long)blockIdx.y * 64;
  long cbase = (long)blockIdx.x * 512;
  int c4 = t & 127;
  int rpar = t >> 7;
  long col0 = cbase + (long)c4 * 4;

  f32x4 csv = *(const f32x4*)(colsum + (long)n * SD + col0);
  f32x4 invc;
  invc[0] = 1.0f / csv[0]; invc[1] = 1.0f / csv[1];
  invc[2] = 1.0f / csv[2]; invc[3] = 1.0f / csv[3];

  unsigned long long cpk[4] = {0ull, 0ull, 0ull, 0ull};

  for (int j = 0; j < 32; ++j) {
    int r = rpar + j * 2;                              // uniform across each wave
    long gr = rbase + r;
    float invr = 1.0f / rowsum[(long)n * LD + gr];
    long idx = ((long)n * LD + gr) * SD + col0;
    f32x4 sv = *(const f32x4*)(sim + idx);
    f32x4 cf, c0v, c1v;
    unsigned long long best = 0ull;
    #pragma unroll
    for (int q = 0; q < 4; ++q) {
      float e = __expf(sv[q]);
      float a0 = e * invc[q];                          // softmax over L (axis=1)
      float a1 = e * invr;                             // softmax over S (axis=2)
      float c = a0 * a1;
      c0v[q] = a0; c1v[q] = a1; cf[q] = c;
      unsigned long long pk = ((unsigned long long)__float_as_uint(c) << 32) |
                              (unsigned int)(~(unsigned int)(col0 + q));
      best = pk > best ? pk : best;
      cpk[q] = pk > cpk[q] ? pk : cpk[q];
    }
    *(f32x4*)(conf + idx) = cf;
    *(f32x4*)(conf0 + idx) = c0v;
    *(f32x4*)(conf1 + idx) = c1v;
    // all 64 lanes of a wave share row r -> wave-level max reduce, one LDS atomic
    #pragma unroll
    for (int d = 1; d < 64; d <<= 1) {
      unsigned long long o = __shfl_xor(best, d);
      best = o > best ? o : best;
    }
    if ((t & 63) == 0) atomicMax(&rmx[r], best);
  }
  #pragma unroll
  for (int q = 0; q < 4; ++q) atomicMax(&cmx[c4 * 4 + q], cpk[q]);
  __syncthreads();
  if (t < 64) atomicMax(&rowpack[(long)n * LD + rbase + t], rmx[t]);
  atomicMax(&colpack[(long)n * SD + cbase + t], cmx[t]);
  atomicMax(&colpack[(long)n * SD + cbase + 256 + t], cmx[t + 256]);
}

// ---------------- Kernel 4: finalize mutual-NN match outputs ----------------
__global__ __launch_bounds__(256) void k_final(const unsigned long long* __restrict__ rowpack,
                                               const unsigned long long* __restrict__ colpack,
                                               float* __restrict__ maskv,
                                               float* __restrict__ jids,
                                               float* __restrict__ mconf) {
  long idx = (long)blockIdx.x * 256 + threadIdx.x;
  if (idx >= (long)NB * LD) return;
  int n = (int)(idx / LD);
  unsigned long long rp = rowpack[idx];
  unsigned int cbits = (unsigned int)(rp >> 32);
  float cval = __uint_as_float(cbits);
  unsigned int col = ~(unsigned int)rp;
  bool valid = (cval > THRV) && (col < (unsigned int)SD);
  if (valid) {
    unsigned long long cp = colpack[(long)n * SD + col];
    valid = ((unsigned int)(cp >> 32)) == cbits;       // conf == colmax
  }
  maskv[idx] = valid ? 1.0f : 0.0f;
  jids[idx]  = valid ? (float)col : 0.0f;
  mconf[idx] = valid ? cval : 0.0f;
}

extern "C" void kernel_launch(void* const* d_in, const int* in_sizes, int n_in,
                              void* d_out, int out_size, void* d_ws, size_t ws_size,
                              hipStream_t stream) {
  const float* f0 = (const float*)d_in[0];
  const float* f1 = (const float*)d_in[1];
  float* out = (float*)d_out;
  float* conf  = out;                  // chunk 0
  float* conf0 = out + CHUNK;          // chunk 1
  float* conf1 = out + 2 * CHUNK;      // chunk 2
  float* simo  = out + 3 * CHUNK;      // chunk 3
  float* maskv = out + 4 * CHUNK;      // [N,L]
  float* jids  = maskv + (long)NB * LD;
  float* mconf = jids + (long)NB * LD;

  // Small accumulators in ws (384 KiB, zeroed every call)
  char* ws = (char*)d_ws;
  float* rowsum = (float*)ws;                                   // 64 KiB
  float* colsum = (float*)(ws + 65536);                         // 64 KiB
  unsigned long long* rowpack = (unsigned long long*)(ws + 131072);  // 128 KiB
  unsigned long long* colpack = (unsigned long long*)(ws + 262144);  // 128 KiB
  hipMemsetAsync(d_ws, 0, 393216, stream);

  // bf16 staging + sq norms live in the conf chunk (rewritten later by k_softmax)
  unsigned short* abf = (unsigned short*)conf;                       // 8 MiB
  unsigned short* bbf = (unsigned short*)((char*)conf + 8388608);    // 8 MiB
  float* sq0 = (float*)((char*)conf + 16777216);                     // 64 KiB
  float* sq1 = (float*)((char*)conf + 16777216 + 65536);             // 64 KiB

  k_prep<<<dim3((NB * (LD + SD)) / 4), dim3(256), 0, stream>>>(f0, f1, abf, bbf, sq0, sq1);
  k_gemm<<<dim3(SD / 128, LD / 128, NB), dim3(256), 0, stream>>>(abf, bbf, sq0, sq1,
                                                                 simo, rowsum, colsum);
  k_softmax<<<dim3(SD / 512, LD / 64, NB), dim3(256), 0, stream>>>(simo, rowsum, colsum,
                                                                   conf, conf0, conf1,
                                                                   rowpack, colpack);
  k_final<<<dim3((NB * LD + 255) / 256), dim3(256), 0, stream>>>(rowpack, colpack,
                                                                 maskv, jids, mconf);
}